// Round 5
// baseline (62.319 us; speedup 1.0000x reference)
//
#include <hip/hip_runtime.h>

#define DD 2048
#define MHH 32

// Blocks 0..DD/4-1: y[row] = relu(dot(W[row,:], x) + b[row]), one wave per row.
// Block DD/4 (last): computes the meta-linear collapse sums:
//   sums = { SA = sum A*V2, SB = sum B*V2, K1 = sum bm1*V2, K2 = sum C*V2 }.
__global__ __launch_bounds__(256) void gemv_relu_prep_k(const float* __restrict__ W,
                                                        const float* __restrict__ x,
                                                        const float* __restrict__ b,
                                                        float* __restrict__ y,
                                                        const float* __restrict__ Wm1,
                                                        const float* __restrict__ bm1,
                                                        const float* __restrict__ Wm2,
                                                        float* __restrict__ sums) {
    if (blockIdx.x == DD / 4) {
        if (threadIdx.x >= 64) return;
        const int lane = threadIdx.x;          // lanes 0..31 carry data
        float sa = 0.f, sb = 0.f, k1 = 0.f, k2 = 0.f;
        if (lane < MHH) {
            const float v2 = Wm2[lane];
            sa = Wm1[lane] * v2;
            sb = Wm1[MHH + lane] * v2;
            k2 = Wm1[2 * MHH + lane] * v2;
            k1 = bm1[lane] * v2;
        }
#pragma unroll
        for (int off = 16; off > 0; off >>= 1) {
            sa += __shfl_down(sa, off, 64);
            sb += __shfl_down(sb, off, 64);
            k1 += __shfl_down(k1, off, 64);
            k2 += __shfl_down(k2, off, 64);
        }
        if (lane == 0) {
            sums[0] = sa; sums[1] = sb; sums[2] = k1; sums[3] = k2;
        }
        return;
    }
    const int wave = threadIdx.x >> 6;
    const int lane = threadIdx.x & 63;
    const int row  = (blockIdx.x << 2) + wave;
    const float* Wr = W + (size_t)row * DD;
    float acc = 0.f;
#pragma unroll
    for (int it = 0; it < 8; ++it) {
        const int col = ((it << 6) + lane) << 2;       // float4 index, coalesced
        const float4 w4 = *reinterpret_cast<const float4*>(Wr + col);
        const float4 x4 = *reinterpret_cast<const float4*>(x + col);
        acc = fmaf(w4.x, x4.x, acc);
        acc = fmaf(w4.y, x4.y, acc);
        acc = fmaf(w4.z, x4.z, acc);
        acc = fmaf(w4.w, x4.w, acc);
    }
#pragma unroll
    for (int off = 32; off > 0; off >>= 1)
        acc += __shfl_down(acc, off, 64);
    if (lane == 0) {
        const float v = acc + b[row];
        y[row] = fmaxf(v, 0.f);
    }
}

// Plain gemv+relu for layers 2 and 3.
__global__ __launch_bounds__(256) void gemv_relu_k(const float* __restrict__ W,
                                                   const float* __restrict__ x,
                                                   const float* __restrict__ b,
                                                   float* __restrict__ y) {
    const int wave = threadIdx.x >> 6;
    const int lane = threadIdx.x & 63;
    const int row  = (blockIdx.x << 2) + wave;
    const float* Wr = W + (size_t)row * DD;
    float acc = 0.f;
#pragma unroll
    for (int it = 0; it < 8; ++it) {
        const int col = ((it << 6) + lane) << 2;
        const float4 w4 = *reinterpret_cast<const float4*>(Wr + col);
        const float4 x4 = *reinterpret_cast<const float4*>(x + col);
        acc = fmaf(w4.x, x4.x, acc);
        acc = fmaf(w4.y, x4.y, acc);
        acc = fmaf(w4.z, x4.z, acc);
        acc = fmaf(w4.w, x4.w, acc);
    }
#pragma unroll
    for (int off = 32; off > 0; off >>= 1)
        acc += __shfl_down(acc, off, 64);
    if (lane == 0) {
        const float v = acc + b[row];
        y[row] = fmaxf(v, 0.f);
    }
}

// nW[o,i] = bm2 + sum_m V2[m]*relu(q_m),  q_m = inp_i*A[m] + W[o,i]*B[m] + P[m]
// Using relu(q) = 0.5*(q + |q|):
//   nW[o,i] = bm2 + 0.5*(lin_i + sum_m |q_m|*V2[m])
//   lin_i   = inp_i*SA + W[o,i]*SB + SP,  SP = K1 + ov*K2   (precomputed sums)
// Inner loop = 3 VALU per (elem, m). P[32] pinned to VGPRs; launch_bounds(256,2)
// gives the allocator ~128-reg headroom so P is NOT spilled to scratch (the
// compiler's default 8-wave/SIMD heuristic capped VGPRs at 64 and spilled).
// The linear half is computed AFTER the abs loop so its 8 regs aren't live
// across the loop.
__global__ __launch_bounds__(256, 2) void meta_k(const float* __restrict__ W1,
                                                 const float* __restrict__ W2,
                                                 const float* __restrict__ W3,
                                                 const float* __restrict__ a0,
                                                 const float* __restrict__ a1,
                                                 const float* __restrict__ a2,
                                                 const float* __restrict__ a3,
                                                 const float* __restrict__ Wm1,
                                                 const float* __restrict__ bm1,
                                                 const float* __restrict__ Wm2,
                                                 const float* __restrict__ bm2,
                                                 const float* __restrict__ sums,
                                                 float* __restrict__ nW) {
    const int layer = blockIdx.x >> 11;          // 2048 rows per layer
    const int row   = blockIdx.x & (DD - 1);

    const float* W   = (layer == 0) ? W1 : (layer == 1) ? W2 : W3;
    const float* inp = (layer == 0) ? a0 : (layer == 1) ? a1 : a2;
    const float* oup = (layer == 0) ? a1 : (layer == 1) ? a2 : a3;

    const float* Wr  = W  + (size_t)row * DD;
    float*       nWr = nW + (size_t)layer * DD * DD + (size_t)row * DD;

    // Hoist all global loads before the compute block.
    const int col0 = threadIdx.x * 4;            // first half, coalesced float4
    const int col1 = (DD / 2) + threadIdx.x * 4; // second half
    const float4 w4a = *reinterpret_cast<const float4*>(Wr + col0);
    const float4 u4a = *reinterpret_cast<const float4*>(inp + col0);
    const float4 w4b = *reinterpret_cast<const float4*>(Wr + col1);
    const float4 u4b = *reinterpret_cast<const float4*>(inp + col1);

    const float ov = oup[row];

    // A, B, V2 are wave-uniform -> SGPRs. P must be VGPR-resident (each fma
    // already carries one SGPR operand).
    float A[MHH], B[MHH], P[MHH], V2[MHH];
#pragma unroll
    for (int m = 0; m < MHH; ++m) {
        A[m]  = Wm1[m];                 // Wm1[0,m]
        B[m]  = Wm1[MHH + m];           // Wm1[1,m]
        V2[m] = Wm2[m];
        P[m]  = fmaf(ov, Wm1[2 * MHH + m], bm1[m]);
        asm volatile("" : "+v"(P[m]));
    }

    // Abs half: c_e = sum_m |q_m| * V2[m].
    float c0 = 0.f, c1 = 0.f, c2 = 0.f, c3 = 0.f;
    float c4 = 0.f, c5 = 0.f, c6 = 0.f, c7 = 0.f;
#pragma unroll
    for (int m = 0; m < MHH; ++m) {
        float t0 = fmaf(u4a.x, A[m], P[m]);
        float t1 = fmaf(u4a.y, A[m], P[m]);
        float t2 = fmaf(u4a.z, A[m], P[m]);
        float t3 = fmaf(u4a.w, A[m], P[m]);
        float t4 = fmaf(u4b.x, A[m], P[m]);
        float t5 = fmaf(u4b.y, A[m], P[m]);
        float t6 = fmaf(u4b.z, A[m], P[m]);
        float t7 = fmaf(u4b.w, A[m], P[m]);
        t0 = fmaf(w4a.x, B[m], t0);
        t1 = fmaf(w4a.y, B[m], t1);
        t2 = fmaf(w4a.z, B[m], t2);
        t3 = fmaf(w4a.w, B[m], t3);
        t4 = fmaf(w4b.x, B[m], t4);
        t5 = fmaf(w4b.y, B[m], t5);
        t6 = fmaf(w4b.z, B[m], t6);
        t7 = fmaf(w4b.w, B[m], t7);
        c0 = fmaf(__builtin_fabsf(t0), V2[m], c0);
        c1 = fmaf(__builtin_fabsf(t1), V2[m], c1);
        c2 = fmaf(__builtin_fabsf(t2), V2[m], c2);
        c3 = fmaf(__builtin_fabsf(t3), V2[m], c3);
        c4 = fmaf(__builtin_fabsf(t4), V2[m], c4);
        c5 = fmaf(__builtin_fabsf(t5), V2[m], c5);
        c6 = fmaf(__builtin_fabsf(t6), V2[m], c6);
        c7 = fmaf(__builtin_fabsf(t7), V2[m], c7);
    }

    // Linear half (after the loop so these regs aren't live across it):
    // lin_e = u*SA + w*SB + SP.
    const float SA = sums[0], SB = sums[1];
    const float SP = fmaf(ov, sums[3], sums[2]);
    const float bias2 = bm2[0];

    float l0 = fmaf(u4a.x, SA, SP), l1 = fmaf(u4a.y, SA, SP);
    float l2 = fmaf(u4a.z, SA, SP), l3 = fmaf(u4a.w, SA, SP);
    float l4 = fmaf(u4b.x, SA, SP), l5 = fmaf(u4b.y, SA, SP);
    float l6 = fmaf(u4b.z, SA, SP), l7 = fmaf(u4b.w, SA, SP);
    l0 = fmaf(w4a.x, SB, l0); l1 = fmaf(w4a.y, SB, l1);
    l2 = fmaf(w4a.z, SB, l2); l3 = fmaf(w4a.w, SB, l3);
    l4 = fmaf(w4b.x, SB, l4); l5 = fmaf(w4b.y, SB, l5);
    l6 = fmaf(w4b.z, SB, l6); l7 = fmaf(w4b.w, SB, l7);

    float4 r0, r1;
    r0.x = fmaf(0.5f, l0 + c0, bias2);
    r0.y = fmaf(0.5f, l1 + c1, bias2);
    r0.z = fmaf(0.5f, l2 + c2, bias2);
    r0.w = fmaf(0.5f, l3 + c3, bias2);
    r1.x = fmaf(0.5f, l4 + c4, bias2);
    r1.y = fmaf(0.5f, l5 + c5, bias2);
    r1.z = fmaf(0.5f, l6 + c6, bias2);
    r1.w = fmaf(0.5f, l7 + c7, bias2);
    *reinterpret_cast<float4*>(nWr + col0) = r0;
    *reinterpret_cast<float4*>(nWr + col1) = r1;
}

extern "C" void kernel_launch(void* const* d_in, const int* in_sizes, int n_in,
                              void* d_out, int out_size, void* d_ws, size_t ws_size,
                              hipStream_t stream) {
    const float* x   = (const float*)d_in[0];
    const float* W1  = (const float*)d_in[1];
    const float* b1  = (const float*)d_in[2];
    const float* W2  = (const float*)d_in[3];
    const float* b2  = (const float*)d_in[4];
    const float* W3  = (const float*)d_in[5];
    const float* b3  = (const float*)d_in[6];
    const float* Wm1 = (const float*)d_in[7];
    const float* bm1 = (const float*)d_in[8];
    const float* Wm2 = (const float*)d_in[9];
    const float* bm2 = (const float*)d_in[10];

    float* out  = (float*)d_out;           // out: [2048]
    float* nW   = out + DD;                // nW1|nW2|nW3: 3 x 2048 x 2048
    float* a1   = (float*)d_ws;            // [2048]
    float* a2   = a1 + DD;                 // [2048]
    float* sums = a2 + DD;                 // [4]

    gemv_relu_prep_k<<<DD / 4 + 1, 256, 0, stream>>>(W1, x, b1, a1, Wm1, bm1, Wm2, sums);
    gemv_relu_k<<<DD / 4, 256, 0, stream>>>(W2, a1, b2, a2);
    gemv_relu_k<<<DD / 4, 256, 0, stream>>>(W3, a2, b3, out);
    meta_k<<<3 * DD, 256, 0, stream>>>(W1, W2, W3, x, a1, a2, out,
                                       Wm1, bm1, Wm2, bm2, sums, nW);
}

// Round 6
// 54.317 us; speedup vs baseline: 1.1473x; 1.1473x over previous
//
#include <hip/hip_runtime.h>

#define DD 2048
#define MHH 32

typedef _Float16 hf2 __attribute__((ext_vector_type(2)));

__device__ __forceinline__ hf2 sgpr_pair(float lo, float hi) {
    hf2 v;
    v.x = (_Float16)lo;
    v.y = (_Float16)hi;
    unsigned int bits = __builtin_bit_cast(unsigned int, v);
    bits = __builtin_amdgcn_readfirstlane(bits);   // force SGPR residency
    return __builtin_bit_cast(hf2, bits);
}

__device__ __forceinline__ hf2 dup16(float x) {
    hf2 v;
    v.x = (_Float16)x;
    v.y = v.x;
    return v;
}

// y[row] = relu(dot(W[row,:], x) + b[row]); one wave (64 lanes) per row.
__global__ __launch_bounds__(256) void gemv_relu_k(const float* __restrict__ W,
                                                   const float* __restrict__ x,
                                                   const float* __restrict__ b,
                                                   float* __restrict__ y) {
    const int wave = threadIdx.x >> 6;
    const int lane = threadIdx.x & 63;
    const int row  = (blockIdx.x << 2) + wave;
    const float* Wr = W + (size_t)row * DD;
    float acc = 0.f;
#pragma unroll
    for (int it = 0; it < 8; ++it) {
        const int col = ((it << 6) + lane) << 2;       // float4 index, coalesced
        const float4 w4 = *reinterpret_cast<const float4*>(Wr + col);
        const float4 x4 = *reinterpret_cast<const float4*>(x + col);
        acc = fmaf(w4.x, x4.x, acc);
        acc = fmaf(w4.y, x4.y, acc);
        acc = fmaf(w4.z, x4.z, acc);
        acc = fmaf(w4.w, x4.w, acc);
    }
#pragma unroll
    for (int off = 32; off > 0; off >>= 1)
        acc += __shfl_down(acc, off, 64);
    if (lane == 0) {
        const float v = acc + b[row];
        y[row] = fmaxf(v, 0.f);
    }
}

// nW[o,i] = bm2 + sum_m V2[m]*relu(q_m),  q_m = inp_i*A[m] + W[o,i]*B[m] + P[m]
// f16-packed over m-PAIRS (the reduction dim), f32 accumulation via
// v_dot2_f32_f16. Per (element, m-pair): 4 packed VALU ops:
//   q  = v_pk_fma_f16(u_dup, A_pair, P_pair)   (1 SGPR operand: A)
//   q  = v_pk_fma_f16(w_dup, B_pair, q)        (1 SGPR operand: B)
//   q  = v_pk_max_f16(q, 0)
//   acc= v_dot2_f32_f16(q, V2_pair, acc)       (f32 accumulate)
// A/B/V2 pairs forced to SGPRs via readfirstlane; P pairs pinned in VGPRs.
__global__ __launch_bounds__(256) void meta_k(const float* __restrict__ W1,
                                              const float* __restrict__ W2,
                                              const float* __restrict__ W3,
                                              const float* __restrict__ a0,
                                              const float* __restrict__ a1,
                                              const float* __restrict__ a2,
                                              const float* __restrict__ a3,
                                              const float* __restrict__ Wm1,
                                              const float* __restrict__ bm1,
                                              const float* __restrict__ Wm2,
                                              const float* __restrict__ bm2,
                                              float* __restrict__ nW) {
    const int layer = blockIdx.x >> 11;          // 2048 rows per layer
    const int row   = blockIdx.x & (DD - 1);

    const float* W   = (layer == 0) ? W1 : (layer == 1) ? W2 : W3;
    const float* inp = (layer == 0) ? a0 : (layer == 1) ? a1 : a2;
    const float* oup = (layer == 0) ? a1 : (layer == 1) ? a2 : a3;

    const float* Wr  = W  + (size_t)row * DD;
    float*       nWr = nW + (size_t)layer * DD * DD + (size_t)row * DD;

    const int col0 = threadIdx.x * 4;            // first half, coalesced float4
    const int col1 = (DD / 2) + threadIdx.x * 4; // second half
    const float4 w4a = *reinterpret_cast<const float4*>(Wr + col0);
    const float4 u4a = *reinterpret_cast<const float4*>(inp + col0);
    const float4 w4b = *reinterpret_cast<const float4*>(Wr + col1);
    const float4 u4b = *reinterpret_cast<const float4*>(inp + col1);

    const float ov = oup[row];

    // Packed-pair constants. A/B/V2 wave-uniform -> SGPR; P per-row -> VGPR.
    hf2 Ap[MHH / 2], Bp[MHH / 2], Vp[MHH / 2], Pp[MHH / 2];
#pragma unroll
    for (int mp = 0; mp < MHH / 2; ++mp) {
        const int m = 2 * mp;
        Ap[mp] = sgpr_pair(Wm1[m],        Wm1[m + 1]);        // Wm1[0,m]
        Bp[mp] = sgpr_pair(Wm1[MHH + m],  Wm1[MHH + m + 1]);  // Wm1[1,m]
        Vp[mp] = sgpr_pair(Wm2[m],        Wm2[m + 1]);
        const float p0 = fmaf(ov, Wm1[2 * MHH + m],     bm1[m]);
        const float p1 = fmaf(ov, Wm1[2 * MHH + m + 1], bm1[m + 1]);
        Pp[mp].x = (_Float16)p0;
        Pp[mp].y = (_Float16)p1;
        asm volatile("" : "+v"(Pp[mp]));   // keep P in VGPR (pairs with SGPR A/B)
    }
    const float bias2 = bm2[0];

    // Duplicated-element f16 operands.
    hf2 u0 = dup16(u4a.x), u1 = dup16(u4a.y), u2 = dup16(u4a.z), u3 = dup16(u4a.w);
    hf2 u4 = dup16(u4b.x), u5 = dup16(u4b.y), u6 = dup16(u4b.z), u7 = dup16(u4b.w);
    hf2 w0 = dup16(w4a.x), w1 = dup16(w4a.y), w2 = dup16(w4a.z), w3 = dup16(w4a.w);
    hf2 w4 = dup16(w4b.x), w5 = dup16(w4b.y), w6 = dup16(w4b.z), w7 = dup16(w4b.w);

    float c0 = 0.f, c1 = 0.f, c2 = 0.f, c3 = 0.f;
    float c4 = 0.f, c5 = 0.f, c6 = 0.f, c7 = 0.f;
    const hf2 zero = (hf2)(_Float16)0.f;

#pragma unroll
    for (int mp = 0; mp < MHH / 2; ++mp) {
        const hf2 a = Ap[mp], b = Bp[mp], v = Vp[mp], p = Pp[mp];
        hf2 q0 = __builtin_elementwise_fma(u0, a, p);
        hf2 q1 = __builtin_elementwise_fma(u1, a, p);
        hf2 q2 = __builtin_elementwise_fma(u2, a, p);
        hf2 q3 = __builtin_elementwise_fma(u3, a, p);
        hf2 q4 = __builtin_elementwise_fma(u4, a, p);
        hf2 q5 = __builtin_elementwise_fma(u5, a, p);
        hf2 q6 = __builtin_elementwise_fma(u6, a, p);
        hf2 q7 = __builtin_elementwise_fma(u7, a, p);
        q0 = __builtin_elementwise_fma(w0, b, q0);
        q1 = __builtin_elementwise_fma(w1, b, q1);
        q2 = __builtin_elementwise_fma(w2, b, q2);
        q3 = __builtin_elementwise_fma(w3, b, q3);
        q4 = __builtin_elementwise_fma(w4, b, q4);
        q5 = __builtin_elementwise_fma(w5, b, q5);
        q6 = __builtin_elementwise_fma(w6, b, q6);
        q7 = __builtin_elementwise_fma(w7, b, q7);
        q0 = __builtin_elementwise_max(q0, zero);
        q1 = __builtin_elementwise_max(q1, zero);
        q2 = __builtin_elementwise_max(q2, zero);
        q3 = __builtin_elementwise_max(q3, zero);
        q4 = __builtin_elementwise_max(q4, zero);
        q5 = __builtin_elementwise_max(q5, zero);
        q6 = __builtin_elementwise_max(q6, zero);
        q7 = __builtin_elementwise_max(q7, zero);
        c0 = __builtin_amdgcn_fdot2(q0, v, c0, false);
        c1 = __builtin_amdgcn_fdot2(q1, v, c1, false);
        c2 = __builtin_amdgcn_fdot2(q2, v, c2, false);
        c3 = __builtin_amdgcn_fdot2(q3, v, c3, false);
        c4 = __builtin_amdgcn_fdot2(q4, v, c4, false);
        c5 = __builtin_amdgcn_fdot2(q5, v, c5, false);
        c6 = __builtin_amdgcn_fdot2(q6, v, c6, false);
        c7 = __builtin_amdgcn_fdot2(q7, v, c7, false);
    }

    float4 r0, r1;
    r0.x = c0 + bias2; r0.y = c1 + bias2; r0.z = c2 + bias2; r0.w = c3 + bias2;
    r1.x = c4 + bias2; r1.y = c5 + bias2; r1.z = c6 + bias2; r1.w = c7 + bias2;
    *reinterpret_cast<float4*>(nWr + col0) = r0;
    *reinterpret_cast<float4*>(nWr + col1) = r1;
}

extern "C" void kernel_launch(void* const* d_in, const int* in_sizes, int n_in,
                              void* d_out, int out_size, void* d_ws, size_t ws_size,
                              hipStream_t stream) {
    const float* x   = (const float*)d_in[0];
    const float* W1  = (const float*)d_in[1];
    const float* b1  = (const float*)d_in[2];
    const float* W2  = (const float*)d_in[3];
    const float* b2  = (const float*)d_in[4];
    const float* W3  = (const float*)d_in[5];
    const float* b3  = (const float*)d_in[6];
    const float* Wm1 = (const float*)d_in[7];
    const float* bm1 = (const float*)d_in[8];
    const float* Wm2 = (const float*)d_in[9];
    const float* bm2 = (const float*)d_in[10];

    float* out = (float*)d_out;            // out: [2048]
    float* nW  = out + DD;                 // nW1|nW2|nW3: 3 x 2048 x 2048
    float* a1  = (float*)d_ws;             // [2048]
    float* a2  = a1 + DD;                  // [2048]

    gemv_relu_k<<<DD / 4, 256, 0, stream>>>(W1, x,  b1, a1);
    gemv_relu_k<<<DD / 4, 256, 0, stream>>>(W2, a1, b2, a2);
    gemv_relu_k<<<DD / 4, 256, 0, stream>>>(W3, a2, b3, out);
    meta_k<<<3 * DD, 256, 0, stream>>>(W1, W2, W3, x, a1, a2, out,
                                       Wm1, bm1, Wm2, bm2, nW);
}

// Round 7
// 47.452 us; speedup vs baseline: 1.3133x; 1.1447x over previous
//
#include <hip/hip_runtime.h>

#define DD 2048
#define MHH 32

typedef _Float16 hf2 __attribute__((ext_vector_type(2)));

__device__ __forceinline__ unsigned pack_pair(float lo, float hi) {
    hf2 v;
    v.x = (_Float16)lo;
    v.y = (_Float16)hi;
    return __builtin_bit_cast(unsigned, v);
}

__device__ __forceinline__ hf2 rfl2(unsigned u) {
    u = __builtin_amdgcn_readfirstlane(u);     // force SGPR residency
    return __builtin_bit_cast(hf2, u);
}

__device__ __forceinline__ hf2 dup16(float x) {
    hf2 v;
    v.x = (_Float16)x;
    v.y = v.x;
    return v;
}

// Blocks 0..DD/4-1: y[row] = relu(dot(W[row,:], x) + b[row]), one wave per row.
// Block DD/4: packs the meta constants into f16x2 pairs (consumed by meta_k):
//   cst[0..15]=A pairs, [16..31]=B pairs, [32..47]=V2 pairs,
//   [48..63]=C pairs (Wm1[2,:]), [64..79]=bm1 pairs.
__global__ __launch_bounds__(256) void gemv_relu_prep_k(const float* __restrict__ W,
                                                        const float* __restrict__ x,
                                                        const float* __restrict__ b,
                                                        float* __restrict__ y,
                                                        const float* __restrict__ Wm1,
                                                        const float* __restrict__ bm1,
                                                        const float* __restrict__ Wm2,
                                                        unsigned* __restrict__ cst) {
    if (blockIdx.x == DD / 4) {
        const int mp = threadIdx.x;
        if (mp < MHH / 2) {
            const int m = 2 * mp;
            cst[mp]      = pack_pair(Wm1[m],           Wm1[m + 1]);            // A
            cst[16 + mp] = pack_pair(Wm1[MHH + m],     Wm1[MHH + m + 1]);      // B
            cst[32 + mp] = pack_pair(Wm2[m],           Wm2[m + 1]);            // V2
            cst[48 + mp] = pack_pair(Wm1[2 * MHH + m], Wm1[2 * MHH + m + 1]);  // C
            cst[64 + mp] = pack_pair(bm1[m],           bm1[m + 1]);            // bm1
        }
        return;
    }
    const int wave = threadIdx.x >> 6;
    const int lane = threadIdx.x & 63;
    const int row  = (blockIdx.x << 2) + wave;
    const float* Wr = W + (size_t)row * DD;
    float acc = 0.f;
#pragma unroll
    for (int it = 0; it < 8; ++it) {
        const int col = ((it << 6) + lane) << 2;       // float4 index, coalesced
        const float4 w4 = *reinterpret_cast<const float4*>(Wr + col);
        const float4 x4 = *reinterpret_cast<const float4*>(x + col);
        acc = fmaf(w4.x, x4.x, acc);
        acc = fmaf(w4.y, x4.y, acc);
        acc = fmaf(w4.z, x4.z, acc);
        acc = fmaf(w4.w, x4.w, acc);
    }
#pragma unroll
    for (int off = 32; off > 0; off >>= 1)
        acc += __shfl_down(acc, off, 64);
    if (lane == 0) {
        const float v = acc + b[row];
        y[row] = fmaxf(v, 0.f);
    }
}

// Plain gemv+relu for layers 2 and 3.
__global__ __launch_bounds__(256) void gemv_relu_k(const float* __restrict__ W,
                                                   const float* __restrict__ x,
                                                   const float* __restrict__ b,
                                                   float* __restrict__ y) {
    const int wave = threadIdx.x >> 6;
    const int lane = threadIdx.x & 63;
    const int row  = (blockIdx.x << 2) + wave;
    const float* Wr = W + (size_t)row * DD;
    float acc = 0.f;
#pragma unroll
    for (int it = 0; it < 8; ++it) {
        const int col = ((it << 6) + lane) << 2;
        const float4 w4 = *reinterpret_cast<const float4*>(Wr + col);
        const float4 x4 = *reinterpret_cast<const float4*>(x + col);
        acc = fmaf(w4.x, x4.x, acc);
        acc = fmaf(w4.y, x4.y, acc);
        acc = fmaf(w4.z, x4.z, acc);
        acc = fmaf(w4.w, x4.w, acc);
    }
#pragma unroll
    for (int off = 32; off > 0; off >>= 1)
        acc += __shfl_down(acc, off, 64);
    if (lane == 0) {
        const float v = acc + b[row];
        y[row] = fmaxf(v, 0.f);
    }
}

// nW[o,i] = bm2 + sum_m V2[m]*relu(q_m),  q_m = inp_i*A[m] + W[o,i]*B[m] + P[m]
// f16-packed over m-pairs, f32 accumulation via v_dot2_f32_f16. Constants come
// PRE-PACKED from the prep block (no per-thread cvt/pack chains): setup is
// 20 uniform uint4 loads + readfirstlane (A/B/V/C -> SGPR) + 16 pk_fma for
// P = bm1 + ov*C (bm1 kept in VGPR so each pk_fma has only one SGPR operand).
__global__ __launch_bounds__(256) void meta_k(const float* __restrict__ W1,
                                              const float* __restrict__ W2,
                                              const float* __restrict__ W3,
                                              const float* __restrict__ a0,
                                              const float* __restrict__ a1,
                                              const float* __restrict__ a2,
                                              const float* __restrict__ a3,
                                              const unsigned* __restrict__ cst,
                                              const float* __restrict__ bm2,
                                              float* __restrict__ nW) {
    const int layer = blockIdx.x >> 11;          // 2048 rows per layer
    const int row   = blockIdx.x & (DD - 1);

    const float* W   = (layer == 0) ? W1 : (layer == 1) ? W2 : W3;
    const float* inp = (layer == 0) ? a0 : (layer == 1) ? a1 : a2;
    const float* oup = (layer == 0) ? a1 : (layer == 1) ? a2 : a3;

    const float* Wr  = W  + (size_t)row * DD;
    float*       nWr = nW + (size_t)layer * DD * DD + (size_t)row * DD;

    const int col0 = threadIdx.x * 4;            // first half, coalesced float4
    const int col1 = (DD / 2) + threadIdx.x * 4; // second half
    const float4 w4a = *reinterpret_cast<const float4*>(Wr + col0);
    const float4 u4a = *reinterpret_cast<const float4*>(inp + col0);
    const float4 w4b = *reinterpret_cast<const float4*>(Wr + col1);
    const float4 u4b = *reinterpret_cast<const float4*>(inp + col1);

    // ---- constants: pre-packed pairs ----
    const uint4* c16 = (const uint4*)cst;
    hf2 Ap[MHH / 2], Bp[MHH / 2], Vp[MHH / 2], Pp[MHH / 2];
#pragma unroll
    for (int j = 0; j < 4; ++j) {               // A: SGPR
        const uint4 t = c16[j];
        Ap[4 * j + 0] = rfl2(t.x); Ap[4 * j + 1] = rfl2(t.y);
        Ap[4 * j + 2] = rfl2(t.z); Ap[4 * j + 3] = rfl2(t.w);
    }
#pragma unroll
    for (int j = 0; j < 4; ++j) {               // B: SGPR
        const uint4 t = c16[4 + j];
        Bp[4 * j + 0] = rfl2(t.x); Bp[4 * j + 1] = rfl2(t.y);
        Bp[4 * j + 2] = rfl2(t.z); Bp[4 * j + 3] = rfl2(t.w);
    }
#pragma unroll
    for (int j = 0; j < 4; ++j) {               // V2: SGPR
        const uint4 t = c16[8 + j];
        Vp[4 * j + 0] = rfl2(t.x); Vp[4 * j + 1] = rfl2(t.y);
        Vp[4 * j + 2] = rfl2(t.z); Vp[4 * j + 3] = rfl2(t.w);
    }
    // P = bm1 + ov*C : C in SGPR, bm1 in VGPR (plain load), result pinned VGPR.
    const float ov = oup[row];
    const hf2 ovd = dup16(ov);
#pragma unroll
    for (int j = 0; j < 4; ++j) {
        const uint4 tc = c16[12 + j];           // C (-> SGPR)
        const uint4 tb = c16[16 + j];           // bm1 (stays VGPR)
        const hf2 c0v = rfl2(tc.x), c1v = rfl2(tc.y), c2v = rfl2(tc.z), c3v = rfl2(tc.w);
        hf2 b0v = __builtin_bit_cast(hf2, tb.x);
        hf2 b1v = __builtin_bit_cast(hf2, tb.y);
        hf2 b2v = __builtin_bit_cast(hf2, tb.z);
        hf2 b3v = __builtin_bit_cast(hf2, tb.w);
        Pp[4 * j + 0] = __builtin_elementwise_fma(ovd, c0v, b0v);
        Pp[4 * j + 1] = __builtin_elementwise_fma(ovd, c1v, b1v);
        Pp[4 * j + 2] = __builtin_elementwise_fma(ovd, c2v, b2v);
        Pp[4 * j + 3] = __builtin_elementwise_fma(ovd, c3v, b3v);
        asm volatile("" : "+v"(Pp[4 * j + 0]), "+v"(Pp[4 * j + 1]),
                          "+v"(Pp[4 * j + 2]), "+v"(Pp[4 * j + 3]));
    }
    const float bias2 = bm2[0];

    // Duplicated-element f16 operands.
    hf2 u0 = dup16(u4a.x), u1 = dup16(u4a.y), u2 = dup16(u4a.z), u3 = dup16(u4a.w);
    hf2 u4 = dup16(u4b.x), u5 = dup16(u4b.y), u6 = dup16(u4b.z), u7 = dup16(u4b.w);
    hf2 w0 = dup16(w4a.x), w1 = dup16(w4a.y), w2 = dup16(w4a.z), w3 = dup16(w4a.w);
    hf2 w4 = dup16(w4b.x), w5 = dup16(w4b.y), w6 = dup16(w4b.z), w7 = dup16(w4b.w);

    float c0 = 0.f, c1 = 0.f, c2 = 0.f, c3 = 0.f;
    float c4 = 0.f, c5 = 0.f, c6 = 0.f, c7 = 0.f;
    const hf2 zero = (hf2)(_Float16)0.f;

#pragma unroll
    for (int mp = 0; mp < MHH / 2; ++mp) {
        const hf2 a = Ap[mp], b = Bp[mp], v = Vp[mp], p = Pp[mp];
        hf2 q0 = __builtin_elementwise_fma(u0, a, p);
        hf2 q1 = __builtin_elementwise_fma(u1, a, p);
        hf2 q2 = __builtin_elementwise_fma(u2, a, p);
        hf2 q3 = __builtin_elementwise_fma(u3, a, p);
        hf2 q4 = __builtin_elementwise_fma(u4, a, p);
        hf2 q5 = __builtin_elementwise_fma(u5, a, p);
        hf2 q6 = __builtin_elementwise_fma(u6, a, p);
        hf2 q7 = __builtin_elementwise_fma(u7, a, p);
        q0 = __builtin_elementwise_fma(w0, b, q0);
        q1 = __builtin_elementwise_fma(w1, b, q1);
        q2 = __builtin_elementwise_fma(w2, b, q2);
        q3 = __builtin_elementwise_fma(w3, b, q3);
        q4 = __builtin_elementwise_fma(w4, b, q4);
        q5 = __builtin_elementwise_fma(w5, b, q5);
        q6 = __builtin_elementwise_fma(w6, b, q6);
        q7 = __builtin_elementwise_fma(w7, b, q7);
        q0 = __builtin_elementwise_max(q0, zero);
        q1 = __builtin_elementwise_max(q1, zero);
        q2 = __builtin_elementwise_max(q2, zero);
        q3 = __builtin_elementwise_max(q3, zero);
        q4 = __builtin_elementwise_max(q4, zero);
        q5 = __builtin_elementwise_max(q5, zero);
        q6 = __builtin_elementwise_max(q6, zero);
        q7 = __builtin_elementwise_max(q7, zero);
        c0 = __builtin_amdgcn_fdot2(q0, v, c0, false);
        c1 = __builtin_amdgcn_fdot2(q1, v, c1, false);
        c2 = __builtin_amdgcn_fdot2(q2, v, c2, false);
        c3 = __builtin_amdgcn_fdot2(q3, v, c3, false);
        c4 = __builtin_amdgcn_fdot2(q4, v, c4, false);
        c5 = __builtin_amdgcn_fdot2(q5, v, c5, false);
        c6 = __builtin_amdgcn_fdot2(q6, v, c6, false);
        c7 = __builtin_amdgcn_fdot2(q7, v, c7, false);
    }

    float4 r0, r1;
    r0.x = c0 + bias2; r0.y = c1 + bias2; r0.z = c2 + bias2; r0.w = c3 + bias2;
    r1.x = c4 + bias2; r1.y = c5 + bias2; r1.z = c6 + bias2; r1.w = c7 + bias2;
    *reinterpret_cast<float4*>(nWr + col0) = r0;
    *reinterpret_cast<float4*>(nWr + col1) = r1;
}

extern "C" void kernel_launch(void* const* d_in, const int* in_sizes, int n_in,
                              void* d_out, int out_size, void* d_ws, size_t ws_size,
                              hipStream_t stream) {
    const float* x   = (const float*)d_in[0];
    const float* W1  = (const float*)d_in[1];
    const float* b1  = (const float*)d_in[2];
    const float* W2  = (const float*)d_in[3];
    const float* b2  = (const float*)d_in[4];
    const float* W3  = (const float*)d_in[5];
    const float* b3  = (const float*)d_in[6];
    const float* Wm1 = (const float*)d_in[7];
    const float* bm1 = (const float*)d_in[8];
    const float* Wm2 = (const float*)d_in[9];
    const float* bm2 = (const float*)d_in[10];

    float* out = (float*)d_out;            // out: [2048]
    float* nW  = out + DD;                 // nW1|nW2|nW3: 3 x 2048 x 2048
    float* a1  = (float*)d_ws;             // [2048]
    float* a2  = a1 + DD;                  // [2048]
    unsigned* cst = (unsigned*)(a2 + DD);  // [80] packed f16x2 constants

    gemv_relu_prep_k<<<DD / 4 + 1, 256, 0, stream>>>(W1, x, b1, a1, Wm1, bm1, Wm2, cst);
    gemv_relu_k<<<DD / 4, 256, 0, stream>>>(W2, a1, b2, a2);
    gemv_relu_k<<<DD / 4, 256, 0, stream>>>(W3, a2, b3, out);
    meta_k<<<3 * DD, 256, 0, stream>>>(W1, W2, W3, x, a1, a2, out,
                                       cst, bm2, nW);
}